// Round 6
// baseline (367.511 us; speedup 1.0000x reference)
//
#include <hip/hip_runtime.h>
#include <cstddef>
#include <cstdint>

#define NB 4
#define ND 512
#define NT 4096
#define NK 4096
#define NBT (NB * NT)
#define KP 1536   // augmented K' = 3*ND: interleaved (xh,eh2)|(xh,el2)|(xl,eh2)
#define BK 64
#define NKT (KP / BK)  // 24 K-tiles
#define CT (NK / 256)  // 16 candidate tiles

typedef __attribute__((ext_vector_type(4))) float f32x4;
typedef __attribute__((ext_vector_type(16))) float f32x16;
typedef __attribute__((ext_vector_type(8))) short short8;
typedef __attribute__((ext_vector_type(8))) unsigned short u16x8;
typedef unsigned short u16;

__device__ inline u16 f2bf_rn(float f) {
  unsigned u = __float_as_uint(f);
  return (u16)((u + 0x7FFFu + ((u >> 16) & 1u)) >> 16);
}
__device__ inline float bf2f(u16 h) {
  return __uint_as_float(((unsigned)h) << 16);
}
__device__ inline void gload16(void* lds_p, const void* g) {
  __builtin_amdgcn_global_load_lds(
      (const __attribute__((address_space(1))) unsigned int*)g,
      (__attribute__((address_space(3))) unsigned int*)lds_p, 16, 0, 0);
}

// ---------------------------------------------------- e conversion + norm --
__global__ void conv_e_kernel(const float* __restrict__ emb,
                              u16* __restrict__ eh2, u16* __restrict__ el2,
                              float* __restrict__ enorm) {
  int row = blockIdx.x * 4 + (threadIdx.x >> 6);
  int l = threadIdx.x & 63;
  const float* e = emb + (size_t)row * ND;
  float s = 0.f;
#pragma unroll
  for (int i = 0; i < ND / 64; ++i) {
    int idx = l + i * 64;
    float v = e[idx];
    s += v * v;
    float v2 = 2.f * v;
    u16 h = f2bf_rn(v2);
    u16 lo = f2bf_rn(v2 - bf2f(h));
    eh2[(size_t)row * ND + idx] = h;
    el2[(size_t)row * ND + idx] = lo;
  }
#pragma unroll
  for (int m = 32; m; m >>= 1) s += __shfl_xor(s, m);
  if (l == 0) enorm[row] = s;
}

// ------------------- x conversion (+ transpose) + sum(x^2) partials --------
__global__ __launch_bounds__(256) void conv_x_kernel(const float* __restrict__ x,
                                                     u16* __restrict__ xh,
                                                     u16* __restrict__ xl,
                                                     float* __restrict__ xsq) {
  __shared__ float tile[64][68];
  const int tid = threadIdx.x;
  const int bt0 = blockIdx.x * 64, d0 = blockIdx.y * 64;
  const int b = bt0 / NT, t0 = bt0 % NT;
  const float* xb = x + (size_t)b * ND * NT;
  float s2 = 0.f;
  {
    const int tt4 = (tid & 15) * 4, ddb = tid >> 4;
#pragma unroll
    for (int p = 0; p < 4; ++p) {
      const int dd = ddb + p * 16;
      float4 v = *(const float4*)&xb[(size_t)(d0 + dd) * NT + t0 + tt4];
      s2 += v.x * v.x + v.y * v.y + v.z * v.z + v.w * v.w;
      *(float4*)&tile[dd][tt4] = v;
    }
  }
  __syncthreads();
  {
    const int t_loc = tid >> 2, dg = tid & 3;
    u16 hs[16], ls[16];
#pragma unroll
    for (int j = 0; j < 16; ++j) {
      float f = tile[dg * 16 + j][t_loc];
      u16 h = f2bf_rn(f);
      hs[j] = h;
      ls[j] = f2bf_rn(f - bf2f(h));
    }
    const size_t base = (size_t)(bt0 + t_loc) * ND + d0 + dg * 16;
    *(u16x8*)&xh[base] = *(const u16x8*)&hs[0];
    *(u16x8*)&xh[base + 8] = *(const u16x8*)&hs[8];
    *(u16x8*)&xl[base] = *(const u16x8*)&ls[0];
    *(u16x8*)&xl[base + 8] = *(const u16x8*)&ls[8];
  }
#pragma unroll
  for (int m = 32; m; m >>= 1) s2 += __shfl_xor(s2, m);
  __shared__ float wsum[4];
  if ((tid & 63) == 0) wsum[tid >> 6] = s2;
  __syncthreads();
  if (tid == 0)
    xsq[blockIdx.y * gridDim.x + blockIdx.x] =
        wsum[0] + wsum[1] + wsum[2] + wsum[3];
}

// ------------------------------------------------- 3-phase GEMM + argmin ---
// 256x256 tile, 8 waves (2M x 4N), BK=64, LDS 128 KiB double-buffered,
// st-swizzle via pre-swizzled global source (T2), counted vmcnt (T3/T4),
// setprio (T5), XCD-bijective swizzle (T1), ONE barrier per phase.
// MFMA shape: 32x32x16 (higher per-cycle rate than 16x16x32, m119).
// K-tile tn -> region r3 = tn%3 (xh*eh2 | xh*el2 | xl*eh2), chunk kc = tn/3.
__device__ __forceinline__ void stage_chunk(
    u16 (&lds)[2][2][256][64], int bn, int j, int tn, const u16* xh,
    const u16* xl, const u16* eh2, const u16* el2, int bt0, int c0g, int w,
    int l) {
  if (tn >= NKT) return;
  const int r3 = tn % 3;
  const int kA = (tn / 3) * BK;
  const bool isA = (j == 0) || (j == 3);
  const u16* src;
  if (isA)
    src = (r3 < 2) ? xh : xl;
  else
    src = (r3 == 1) ? el2 : eh2;
#pragma unroll
  for (int i = 0; i < 2; ++i) {
    const int s = w + i * 8;        // span 0..15 (8 LDS rows each)
    const int rl0 = s * 8;          // chunk-row of lane group 0
    const int rl = rl0 + (l >> 3);  // this lane's chunk-row
    const int slot = l & 7;         // 16B slot within row
    int rowL, rowL0, grow;
    if (isA) {  // chunk rows: j==0 -> {0-63,128-191}; j==3 -> +64
      rowL = ((rl & 63) | ((rl & 64) << 1)) + (j == 3 ? 64 : 0);
      rowL0 = ((rl0 & 63) | ((rl0 & 64) << 1)) + (j == 3 ? 64 : 0);
      grow = bt0 + rowL;
    } else {  // chunk rows: j==1 -> {wn*64+[0,32)}; j==2 -> +32
      rowL = (j == 2 ? 32 : 0) + (rl & 31) + ((rl >> 5) << 6);
      rowL0 = (j == 2 ? 32 : 0) + (rl0 & 31) + ((rl0 >> 5) << 6);
      grow = c0g + rowL;
    }
    const int gslot = slot ^ (rowL & 7);  // pre-swizzled global source
    gload16(&lds[bn][isA ? 0 : 1][rowL0][0],
            &src[(size_t)grow * ND + kA + gslot * 8]);
  }
}

__global__ __launch_bounds__(512, 2) void argmin_gemm_kernel(
    const u16* __restrict__ xh, const u16* __restrict__ xl,
    const u16* __restrict__ eh2, const u16* __restrict__ el2,
    const float* __restrict__ enorm, float* __restrict__ cand_v,
    int* __restrict__ cand_i) {
  __shared__ u16 lds[2][2][256][64];  // [buf][A/B][row][k] = 128 KiB
  const int tid = threadIdx.x;
  const int w = tid >> 6, l = tid & 63;
  const int l31 = l & 31, lhi = l >> 5;
  const int wm = w >> 2, wn = w & 3;
  // XCD-aware bijective swizzle: nwg=1024, 128 blocks per XCD chunk.
  const int id = blockIdx.x;
  const int id_sw = (id & 7) * 128 + (id >> 3);
  const int bx = id_sw & 63, by = id_sw >> 6;
  const int bt0 = bx * 256, c0g = by * 256;

  f32x16 acc[2][2][2];  // [qm][m2][qn], 32x32 tiles
#pragma unroll
  for (int qm = 0; qm < 2; ++qm)
#pragma unroll
    for (int m2 = 0; m2 < 2; ++m2)
#pragma unroll
      for (int qn = 0; qn < 2; ++qn) acc[qm][m2][qn] = (f32x16)0.f;

  short8 aF[2][4], bF0[4], bF1[4];  // [m2][kstep] / [kstep]

#define DS_A(QM)                                                         \
  _Pragma("unroll") for (int m2 = 0; m2 < 2; ++m2) {                     \
    _Pragma("unroll") for (int ks = 0; ks < 4; ++ks) {                   \
      const int row = wm * 128 + (QM) * 64 + m2 * 32 + l31;              \
      const int slot = (ks * 2 + lhi) ^ (row & 7);                       \
      aF[m2][ks] = *(const short8*)&lds[cur][0][row][slot * 8];          \
    }                                                                    \
  }
#define DS_B(QN, BF)                                                     \
  _Pragma("unroll") for (int ks = 0; ks < 4; ++ks) {                     \
    const int row = wn * 64 + (QN) * 32 + l31;                           \
    const int slot = (ks * 2 + lhi) ^ (row & 7);                         \
    BF[ks] = *(const short8*)&lds[cur][1][row][slot * 8];                \
  }
#define MM(QM, QN, BF)                                                   \
  __builtin_amdgcn_s_setprio(1);                                         \
  _Pragma("unroll") for (int m2 = 0; m2 < 2; ++m2) {                     \
    _Pragma("unroll") for (int ks = 0; ks < 4; ++ks) {                   \
      acc[QM][m2][QN] = __builtin_amdgcn_mfma_f32_32x32x16_bf16(         \
          aF[m2][ks], BF[ks], acc[QM][m2][QN], 0, 0, 0);                 \
    }                                                                    \
  }                                                                      \
  __builtin_amdgcn_s_setprio(0);
#define BAR __builtin_amdgcn_s_barrier()
#define LGK                                              \
  asm volatile("s_waitcnt lgkmcnt(0)" ::: "memory");     \
  __builtin_amdgcn_sched_barrier(0)
#define VMC(N) asm volatile("s_waitcnt vmcnt(" #N ")" ::: "memory")

  // prologue: stage all 4 chunks of tile 0 into buf 0 (8 loads/thread);
  // wait until c0,c1 landed (4 outstanding = c2,c3) -> loop invariant.
  stage_chunk(lds, 0, 0, 0, xh, xl, eh2, el2, bt0, c0g, w, l);
  stage_chunk(lds, 0, 1, 0, xh, xl, eh2, el2, bt0, c0g, w, l);
  stage_chunk(lds, 0, 2, 0, xh, xl, eh2, el2, bt0, c0g, w, l);
  stage_chunk(lds, 0, 3, 0, xh, xl, eh2, el2, bt0, c0g, w, l);
  VMC(4);
  BAR;

  // invariant at tile entry: outstanding = 4 loads = {c2(t), c3(t)};
  // c0(t), c1(t) landed (prev phase's counted vmcnt + barrier).
  for (int t = 0; t < NKT; ++t) {
    const int cur = t & 1;
    const int nb = cur ^ 1;
    const int tn = t + 1;
    const bool last = (t == NKT - 1);
    // ---- P0: reads c0 (A qm0), c1 (B qn0); stage c0,c1 of t+1 ----
    DS_A(0);
    DS_B(0, bF0);
    stage_chunk(lds, nb, 0, tn, xh, xl, eh2, el2, bt0, c0g, w, l);
    stage_chunk(lds, nb, 1, tn, xh, xl, eh2, el2, bt0, c0g, w, l);
    LGK;
    MM(0, 0, bF0);
    if (last) {       // out=[c2,c3]: drain c2
      VMC(2);
    } else {          // out=[c2t,c3t,c0n,c1n]=8: drain c2t
      VMC(6);
    }
    BAR;
    // ---- P1: reads c2 (B qn1); stage c2 of t+1 ----
    DS_B(1, bF1);
    stage_chunk(lds, nb, 2, tn, xh, xl, eh2, el2, bt0, c0g, w, l);
    LGK;
    MM(0, 1, bF1);
    if (last) {       // drain c3
      VMC(0);
    } else {          // out=[c3t,c0n,c1n,c2n]=8: drain c3t
      VMC(6);
    }
    BAR;
    // ---- P2: reads c3 (A qm1); 16 MFMA (reuses bF0, bF1); stage c3 ----
    DS_A(1);
    stage_chunk(lds, nb, 3, tn, xh, xl, eh2, el2, bt0, c0g, w, l);
    LGK;
    MM(1, 0, bF0);
    MM(1, 1, bF1);
    if (last) {
      VMC(0);
    } else {          // out=[c0n..c3n]=8: drain c0n,c1n -> invariant
      VMC(4);
    }
    BAR;
  }
#undef DS_A
#undef DS_B
#undef MM
#undef BAR
#undef LGK
#undef VMC

  // ---- epilogue: per-row argmin over this block's 256 cols ----
  __syncthreads();  // all loads drained (vmcnt 0 at exit); LDS reused below
  float* cvs = (float*)&lds[0][0][0][0];  // [4][256]
  int* cis = (int*)(cvs + 4 * 256);       // [4][256]

  // C/D layout (32x32): col = l&31, row = (reg&3) + 8*(reg>>2) + 4*lhi
  const int col0 = c0g + wn * 64 + l31;       // qn=0 col
  const float en0 = enorm[col0];
  const float en1 = enorm[col0 + 32];         // qn=1 col
#pragma unroll
  for (int qm = 0; qm < 2; ++qm)
#pragma unroll
    for (int m2 = 0; m2 < 2; ++m2) {
      float bv[16];
      int bi[16];
#pragma unroll
      for (int reg = 0; reg < 16; ++reg) {
        const float s0 = en0 - acc[qm][m2][0][reg];
        const float s1 = en1 - acc[qm][m2][1][reg];
        const bool t1 = s1 < s0;  // col0 < col0+32; tie keeps col0
        bv[reg] = t1 ? s1 : s0;
        bi[reg] = t1 ? (col0 + 32) : col0;
      }
#pragma unroll
      for (int msk = 1; msk < 32; msk <<= 1) {
#pragma unroll
        for (int reg = 0; reg < 16; ++reg) {
          const float ov = __shfl_xor(bv[reg], msk);
          const int oi = __shfl_xor(bi[reg], msk);
          if (ov < bv[reg] || (ov == bv[reg] && oi < bi[reg])) {
            bv[reg] = ov;
            bi[reg] = oi;
          }
        }
      }
      if (l31 == 0) {
#pragma unroll
        for (int reg = 0; reg < 16; ++reg) {
          const int row = wm * 128 + qm * 64 + m2 * 32 + (reg & 3) +
                          8 * (reg >> 2) + 4 * lhi;
          cvs[wn * 256 + row] = bv[reg];
          cis[wn * 256 + row] = bi[reg];
        }
      }
    }
  __syncthreads();
  if (tid < 256) {
    float v = cvs[tid];
    int bidx = cis[tid];
#pragma unroll
    for (int q = 1; q < 4; ++q) {  // ascending wn -> ascending cols
      const float ov = cvs[q * 256 + tid];
      const int oi = cis[q * 256 + tid];
      if (ov < v) {
        v = ov;
        bidx = oi;
      }
    }
    cand_v[(size_t)by * NBT + bt0 + tid] = v;
    cand_i[(size_t)by * NBT + bt0 + tid] = bidx;
  }
}

// -------- combine + exact fp32 top-2 rescore + loss partial (s_best) -------
__global__ __launch_bounds__(256) void combine_rescore_kernel(
    const float* __restrict__ cand_v, const int* __restrict__ cand_i,
    const float* __restrict__ x, const float* __restrict__ emb,
    const float* __restrict__ enorm, int* __restrict__ idx_ws,
    float* __restrict__ idxf, float* __restrict__ lpart) {
  const int r = blockIdx.x * 256 + threadIdx.x;
  float v1 = INFINITY, v2 = INFINITY;
  int i1 = 0, i2 = 0;
#pragma unroll
  for (int nt = 0; nt < CT; ++nt) {  // ascending nt -> ascending index
    const float v = cand_v[(size_t)nt * NBT + r];
    const int i = cand_i[(size_t)nt * NBT + r];
    if (v < v1) {
      v2 = v1;
      i2 = i1;
      v1 = v;
      i1 = i;
    } else if (v < v2) {
      v2 = v;
      i2 = i;
    }
  }
  const int b = r >> 12, t = r & (NT - 1);
  const float* xb = x + (size_t)b * ND * NT + t;
  const float* e1 = emb + (size_t)i1 * ND;
  const float* e2 = emb + (size_t)i2 * ND;
  float d1 = 0.f, d2 = 0.f;
#pragma unroll 8
  for (int d = 0; d < ND; ++d) {
    const float xv = xb[(size_t)d * NT];
    d1 += xv * e1[d];
    d2 += xv * e2[d];
  }
  const float s1 = enorm[i1] - 2.f * d1;
  const float s2 = enorm[i2] - 2.f * d2;
  const bool take2 = (s2 < s1 || (s2 == s1 && i2 < i1));
  const int best = take2 ? i2 : i1;
  idx_ws[r] = best;
  idxf[r] = (float)best;
  // per-row loss term: sum_d (x-v)^2 - sum_d x^2 = enorm[best] - 2*dot_best
  float lsum = take2 ? s2 : s1;
#pragma unroll
  for (int m = 32; m; m >>= 1) lsum += __shfl_xor(lsum, m);
  __shared__ float wsum[4];
  if ((threadIdx.x & 63) == 0) wsum[threadIdx.x >> 6] = lsum;
  __syncthreads();
  if (threadIdx.x == 0)
    lpart[blockIdx.x] = wsum[0] + wsum[1] + wsum[2] + wsum[3];
}

// ----------------------------------------------- gather (emb -> [B,D,T]) ---
__global__ __launch_bounds__(256) void gather_kernel(
    const float* __restrict__ emb, const int* __restrict__ idx_ws,
    float* __restrict__ vals_out) {
  __shared__ float tile[64][65];
  const int tid = threadIdx.x;
  const int bt0 = blockIdx.x * 64;
  const int d0 = blockIdx.y * 64;
  const int b = bt0 / NT;
  const int t0 = bt0 % NT;
  {
    const int dd4 = (tid & 15) * 4;
    const int ttb = tid >> 4;
#pragma unroll
    for (int p = 0; p < 4; ++p) {
      const int tt = ttb + p * 16;
      const int r = idx_ws[bt0 + tt];
      float4 v = *(const float4*)&emb[(size_t)r * ND + d0 + dd4];
      tile[tt][dd4 + 0] = v.x;
      tile[tt][dd4 + 1] = v.y;
      tile[tt][dd4 + 2] = v.z;
      tile[tt][dd4 + 3] = v.w;
    }
  }
  __syncthreads();
  {
    const int tt4 = (tid & 15) * 4;
    const int ddb = tid >> 4;
#pragma unroll
    for (int p = 0; p < 4; ++p) {
      const int dd = ddb + p * 16;
      float4 v;
      v.x = tile[tt4 + 0][dd];
      v.y = tile[tt4 + 1][dd];
      v.z = tile[tt4 + 2][dd];
      v.w = tile[tt4 + 3][dd];
      const size_t o = (size_t)b * ND * NT + (size_t)(d0 + dd) * NT + t0 + tt4;
      *(float4*)&vals_out[o] = v;
    }
  }
}

// ----------------------------------------------------------------- loss ----
__global__ void loss_kernel(const float* __restrict__ partials, int n,
                            float* __restrict__ out) {
  float s = 0.f;
  for (int i = threadIdx.x; i < n; i += 256) s += partials[i];
#pragma unroll
  for (int m = 32; m; m >>= 1) s += __shfl_xor(s, m);
  __shared__ float wsum[4];
  if ((threadIdx.x & 63) == 0) wsum[threadIdx.x >> 6] = s;
  __syncthreads();
  if (threadIdx.x == 0)
    out[0] = 2.0f * (wsum[0] + wsum[1] + wsum[2] + wsum[3]) /
             (float)((size_t)NB * ND * NT);
}

// --------------------------------------------------------------- launch ----
extern "C" void kernel_launch(void* const* d_in, const int* in_sizes, int n_in,
                              void* d_out, int out_size, void* d_ws,
                              size_t ws_size, hipStream_t stream) {
  const float* x = (const float*)d_in[0];
  const float* emb = (const float*)d_in[1];
  float* out = (float*)d_out;
  float* vals_out = out;                         // [B, D, T]
  float* idxf_out = out + (size_t)NB * ND * NT;  // [B, T] as float
  float* loss_out = idxf_out + NBT;              // scalar

  u16* xh = (u16*)d_ws;                            // NBT*ND
  u16* xl = xh + (size_t)NBT * ND;                 // NBT*ND
  u16* eh2 = xl + (size_t)NBT * ND;                // NK*ND
  u16* el2 = eh2 + (size_t)NK * ND;                // NK*ND
  float* enorm = (float*)(el2 + (size_t)NK * ND);  // NK
  float* cand_v = enorm + NK;                      // CT * NBT
  int* cand_i = (int*)(cand_v + (size_t)CT * NBT);
  int* idx_ws = cand_i + (size_t)CT * NBT;  // NBT
  float* partials = (float*)(idx_ws + NBT); // 2048 (x^2) + 64 (rescore)

  conv_e_kernel<<<NK / 4, 256, 0, stream>>>(emb, eh2, el2, enorm);
  conv_x_kernel<<<dim3(NBT / 64, ND / 64), 256, 0, stream>>>(x, xh, xl,
                                                             partials);
  argmin_gemm_kernel<<<1024, 512, 0, stream>>>(xh, xl, eh2, el2, enorm, cand_v,
                                               cand_i);
  combine_rescore_kernel<<<NBT / 256, 256, 0, stream>>>(
      cand_v, cand_i, x, emb, enorm, idx_ws, idxf_out, partials + 2048);
  gather_kernel<<<dim3(NBT / 64, ND / 64), 256, 0, stream>>>(emb, idx_ws,
                                                             vals_out);
  loss_kernel<<<1, 256, 0, stream>>>(partials, 2048 + 64, loss_out);
}

// Round 7
// 289.373 us; speedup vs baseline: 1.2700x; 1.2700x over previous
//
#include <hip/hip_runtime.h>
#include <cstddef>
#include <cstdint>

#define NB 4
#define ND 512
#define NT 4096
#define NK 4096
#define NBT (NB * NT)
#define KP 1536   // augmented K' = 3*ND: interleaved (xh,eh2)|(xh,el2)|(xl,eh2)
#define BK 64
#define NKT (KP / BK)  // 24 K-tiles
#define CT (NK / 256)  // 16 candidate tiles

typedef __attribute__((ext_vector_type(4))) float f32x4;
typedef __attribute__((ext_vector_type(8))) short short8;
typedef __attribute__((ext_vector_type(8))) unsigned short u16x8;
typedef unsigned short u16;

__device__ inline u16 f2bf_rn(float f) {
  unsigned u = __float_as_uint(f);
  return (u16)((u + 0x7FFFu + ((u >> 16) & 1u)) >> 16);
}
__device__ inline float bf2f(u16 h) {
  return __uint_as_float(((unsigned)h) << 16);
}
__device__ inline void gload16(void* lds_p, const void* g) {
  __builtin_amdgcn_global_load_lds(
      (const __attribute__((address_space(1))) unsigned int*)g,
      (__attribute__((address_space(3))) unsigned int*)lds_p, 16, 0, 0);
}

// ---------------------------------------------------- e conversion + norm --
__global__ void conv_e_kernel(const float* __restrict__ emb,
                              u16* __restrict__ eh2, u16* __restrict__ el2,
                              float* __restrict__ enorm) {
  int row = blockIdx.x * 4 + (threadIdx.x >> 6);
  int l = threadIdx.x & 63;
  const float* e = emb + (size_t)row * ND;
  float s = 0.f;
#pragma unroll
  for (int i = 0; i < ND / 64; ++i) {
    int idx = l + i * 64;
    float v = e[idx];
    s += v * v;
    float v2 = 2.f * v;
    u16 h = f2bf_rn(v2);
    u16 lo = f2bf_rn(v2 - bf2f(h));
    eh2[(size_t)row * ND + idx] = h;
    el2[(size_t)row * ND + idx] = lo;
  }
#pragma unroll
  for (int m = 32; m; m >>= 1) s += __shfl_xor(s, m);
  if (l == 0) enorm[row] = s;
}

// ------------------- x conversion (+ transpose) + sum(x^2) partials --------
__global__ __launch_bounds__(256) void conv_x_kernel(const float* __restrict__ x,
                                                     u16* __restrict__ xh,
                                                     u16* __restrict__ xl,
                                                     float* __restrict__ xsq) {
  __shared__ float tile[64][68];
  const int tid = threadIdx.x;
  const int bt0 = blockIdx.x * 64, d0 = blockIdx.y * 64;
  const int b = bt0 / NT, t0 = bt0 % NT;
  const float* xb = x + (size_t)b * ND * NT;
  float s2 = 0.f;
  {
    const int tt4 = (tid & 15) * 4, ddb = tid >> 4;
#pragma unroll
    for (int p = 0; p < 4; ++p) {
      const int dd = ddb + p * 16;
      float4 v = *(const float4*)&xb[(size_t)(d0 + dd) * NT + t0 + tt4];
      s2 += v.x * v.x + v.y * v.y + v.z * v.z + v.w * v.w;
      *(float4*)&tile[dd][tt4] = v;
    }
  }
  __syncthreads();
  {
    const int t_loc = tid >> 2, dg = tid & 3;
    u16 hs[16], ls[16];
#pragma unroll
    for (int j = 0; j < 16; ++j) {
      float f = tile[dg * 16 + j][t_loc];
      u16 h = f2bf_rn(f);
      hs[j] = h;
      ls[j] = f2bf_rn(f - bf2f(h));
    }
    const size_t base = (size_t)(bt0 + t_loc) * ND + d0 + dg * 16;
    *(u16x8*)&xh[base] = *(const u16x8*)&hs[0];
    *(u16x8*)&xh[base + 8] = *(const u16x8*)&hs[8];
    *(u16x8*)&xl[base] = *(const u16x8*)&ls[0];
    *(u16x8*)&xl[base + 8] = *(const u16x8*)&ls[8];
  }
#pragma unroll
  for (int m = 32; m; m >>= 1) s2 += __shfl_xor(s2, m);
  __shared__ float wsum[4];
  if ((tid & 63) == 0) wsum[tid >> 6] = s2;
  __syncthreads();
  if (tid == 0)
    xsq[blockIdx.y * gridDim.x + blockIdx.x] =
        wsum[0] + wsum[1] + wsum[2] + wsum[3];
}

// ------------------------------------------------- 3-phase GEMM + argmin ---
// 256x256 tile, 8 waves (2M x 4N), BK=64, LDS 128 KiB double-buffered,
// st-swizzle via pre-swizzled global source (T2), counted vmcnt (T3/T4),
// setprio (T5), XCD-bijective swizzle (T1), ONE barrier per phase.
// MFMA 16x16x32 (proven conflict-free fragment reads; r6's 32x32 had
// structural 4-way bank conflicts). Staging for tile t+1 is FRONT-LOADED
// entirely into P0 (issue->consume slack 3-4 phases > HBM latency);
// counted waits VMC(10)/(8)/(4), never 0 in the main loop.
// K-tile tn -> region r3 = tn%3 (xh*eh2 | xh*el2 | xl*eh2), chunk kc = tn/3.
__device__ __forceinline__ void stage_chunk(
    u16 (&lds)[2][2][256][64], int bn, int j, int tn, const u16* xh,
    const u16* xl, const u16* eh2, const u16* el2, int bt0, int c0g, int w,
    int l) {
  if (tn >= NKT) return;
  const int r3 = tn % 3;
  const int kA = (tn / 3) * BK;
  const bool isA = (j == 0) || (j == 3);
  const u16* src;
  if (isA)
    src = (r3 < 2) ? xh : xl;
  else
    src = (r3 == 1) ? el2 : eh2;
#pragma unroll
  for (int i = 0; i < 2; ++i) {
    const int s = w + i * 8;        // span 0..15 (8 LDS rows each)
    const int rl0 = s * 8;          // chunk-row of lane group 0
    const int rl = rl0 + (l >> 3);  // this lane's chunk-row
    const int slot = l & 7;         // 16B slot within row
    int rowL, rowL0, grow;
    if (isA) {  // chunk rows: j==0 -> {0-63,128-191}; j==3 -> +64
      rowL = ((rl & 63) | ((rl & 64) << 1)) + (j == 3 ? 64 : 0);
      rowL0 = ((rl0 & 63) | ((rl0 & 64) << 1)) + (j == 3 ? 64 : 0);
      grow = bt0 + rowL;
    } else {  // chunk rows: j==1 -> {wn*64+[0,32)}; j==2 -> +32
      rowL = (j == 2 ? 32 : 0) + (rl & 31) + ((rl >> 5) << 6);
      rowL0 = (j == 2 ? 32 : 0) + (rl0 & 31) + ((rl0 >> 5) << 6);
      grow = c0g + rowL;
    }
    const int gslot = slot ^ (rowL & 7);  // pre-swizzled global source
    gload16(&lds[bn][isA ? 0 : 1][rowL0][0],
            &src[(size_t)grow * ND + kA + gslot * 8]);
  }
}

__global__ __launch_bounds__(512, 2) void argmin_gemm_kernel(
    const u16* __restrict__ xh, const u16* __restrict__ xl,
    const u16* __restrict__ eh2, const u16* __restrict__ el2,
    const float* __restrict__ enorm, float* __restrict__ cand_v,
    int* __restrict__ cand_i) {
  __shared__ u16 lds[2][2][256][64];  // [buf][A/B][row][k] = 128 KiB
  const int tid = threadIdx.x;
  const int w = tid >> 6, l = tid & 63;
  const int l15 = l & 15, l4 = l >> 4;
  const int wm = w >> 2, wn = w & 3;
  // XCD-aware bijective swizzle: nwg=1024, 128 blocks per XCD chunk.
  const int id = blockIdx.x;
  const int id_sw = (id & 7) * 128 + (id >> 3);
  const int bx = id_sw & 63, by = id_sw >> 6;
  const int bt0 = bx * 256, c0g = by * 256;

  f32x4 acc[2][4][2][2];  // [qm][m][qn][n]
#pragma unroll
  for (int qm = 0; qm < 2; ++qm)
#pragma unroll
    for (int m = 0; m < 4; ++m)
#pragma unroll
      for (int qn = 0; qn < 2; ++qn)
#pragma unroll
        for (int n = 0; n < 2; ++n) acc[qm][m][qn][n] = (f32x4)0.f;

  short8 aF[4][2], bF0[2][2], bF1[2][2];

#define DS_A(QM)                                                         \
  _Pragma("unroll") for (int m = 0; m < 4; ++m) {                        \
    _Pragma("unroll") for (int kf = 0; kf < 2; ++kf) {                   \
      const int row = wm * 128 + (QM) * 64 + m * 16 + l15;               \
      const int slot = (kf * 4 + l4) ^ (row & 7);                        \
      aF[m][kf] = *(const short8*)&lds[cur][0][row][slot * 8];           \
    }                                                                    \
  }
#define DS_B(QN, BF)                                                     \
  _Pragma("unroll") for (int n = 0; n < 2; ++n) {                        \
    _Pragma("unroll") for (int kf = 0; kf < 2; ++kf) {                   \
      const int row = wn * 64 + (QN) * 32 + n * 16 + l15;                \
      const int slot = (kf * 4 + l4) ^ (row & 7);                        \
      BF[n][kf] = *(const short8*)&lds[cur][1][row][slot * 8];           \
    }                                                                    \
  }
#define MM(QM, QN, BF)                                                   \
  __builtin_amdgcn_s_setprio(1);                                         \
  _Pragma("unroll") for (int m = 0; m < 4; ++m) {                        \
    _Pragma("unroll") for (int n = 0; n < 2; ++n) {                      \
      _Pragma("unroll") for (int kf = 0; kf < 2; ++kf) {                 \
        acc[QM][m][QN][n] = __builtin_amdgcn_mfma_f32_16x16x32_bf16(     \
            aF[m][kf], BF[n][kf], acc[QM][m][QN][n], 0, 0, 0);           \
      }                                                                  \
    }                                                                    \
  }                                                                      \
  __builtin_amdgcn_s_setprio(0);
#define BAR __builtin_amdgcn_s_barrier()
#define LGK                                              \
  asm volatile("s_waitcnt lgkmcnt(0)" ::: "memory");     \
  __builtin_amdgcn_sched_barrier(0)
#define VMC(N) asm volatile("s_waitcnt vmcnt(" #N ")" ::: "memory")

  // prologue: stage all 4 chunks of tile 0 into buf 0 (8 loads/thread);
  // wait until c0,c1 landed (4 outstanding = c2,c3) -> loop invariant.
  stage_chunk(lds, 0, 0, 0, xh, xl, eh2, el2, bt0, c0g, w, l);
  stage_chunk(lds, 0, 1, 0, xh, xl, eh2, el2, bt0, c0g, w, l);
  stage_chunk(lds, 0, 2, 0, xh, xl, eh2, el2, bt0, c0g, w, l);
  stage_chunk(lds, 0, 3, 0, xh, xl, eh2, el2, bt0, c0g, w, l);
  VMC(4);
  BAR;

  // invariant at tile entry: outstanding = 4 loads = {c2(t), c3(t)};
  // c0(t), c1(t) landed (prev phase's counted vmcnt + barrier).
  for (int t = 0; t < NKT; ++t) {
    const int cur = t & 1;
    const int nb = cur ^ 1;
    const int tn = t + 1;
    const bool last = (t == NKT - 1);
    // ---- P0: stage ALL of t+1 (issued first for max slack);
    //      reads c0 (A qm0), c1 (B qn0) ----
    stage_chunk(lds, nb, 0, tn, xh, xl, eh2, el2, bt0, c0g, w, l);
    stage_chunk(lds, nb, 1, tn, xh, xl, eh2, el2, bt0, c0g, w, l);
    stage_chunk(lds, nb, 2, tn, xh, xl, eh2, el2, bt0, c0g, w, l);
    stage_chunk(lds, nb, 3, tn, xh, xl, eh2, el2, bt0, c0g, w, l);
    DS_A(0);
    DS_B(0, bF0);
    LGK;
    MM(0, 0, bF0);
    if (last) {       // out=[c2,c3]: drain c2
      VMC(2);
    } else {          // out=[c2t,c3t,c0n..c3n]=12: drain c2t
      VMC(10);
    }
    BAR;
    // ---- P1: reads c2 (B qn1) ----
    DS_B(1, bF1);
    LGK;
    MM(0, 1, bF1);
    if (last) {       // drain c3
      VMC(0);
    } else {          // drain c3t
      VMC(8);
    }
    BAR;
    // ---- P2: reads c3 (A qm1); 32 MFMA (reuses bF0, bF1) ----
    DS_A(1);
    LGK;
    MM(1, 0, bF0);
    MM(1, 1, bF1);
    if (last) {
      VMC(0);
    } else {          // out=[c0n..c3n]=8: drain c0n,c1n -> invariant
      VMC(4);
    }
    BAR;
  }
#undef DS_A
#undef DS_B
#undef MM
#undef BAR
#undef LGK
#undef VMC

  // ---- epilogue: per-row argmin over this block's 256 cols ----
  __syncthreads();  // all loads drained (vmcnt 0 at exit); LDS reused below
  float* cvs = (float*)&lds[0][0][0][0];  // [4][256]
  int* cis = (int*)(cvs + 4 * 256);       // [4][256]

  float bv[2][4][4];
  int bi[2][4][4];
#pragma unroll
  for (int qm = 0; qm < 2; ++qm)
#pragma unroll
    for (int m = 0; m < 4; ++m)
#pragma unroll
      for (int q = 0; q < 4; ++q) {
        bv[qm][m][q] = INFINITY;
        bi[qm][m][q] = 0;
      }
#pragma unroll
  for (int qn = 0; qn < 2; ++qn)  // ascending col order -> first-min ties
#pragma unroll
    for (int n = 0; n < 2; ++n) {
      const int col = c0g + wn * 64 + qn * 32 + n * 16 + l15;
      const float en = enorm[col];
#pragma unroll
      for (int qm = 0; qm < 2; ++qm)
#pragma unroll
        for (int m = 0; m < 4; ++m)
#pragma unroll
          for (int q = 0; q < 4; ++q) {
            const float s = en - acc[qm][m][qn][n][q];
            if (s < bv[qm][m][q]) {
              bv[qm][m][q] = s;
              bi[qm][m][q] = col;
            }
          }
    }
#pragma unroll
  for (int msk = 1; msk < 16; msk <<= 1) {
#pragma unroll
    for (int qm = 0; qm < 2; ++qm)
#pragma unroll
      for (int m = 0; m < 4; ++m)
#pragma unroll
        for (int q = 0; q < 4; ++q) {
          const float ov = __shfl_xor(bv[qm][m][q], msk);
          const int oi = __shfl_xor(bi[qm][m][q], msk);
          if (ov < bv[qm][m][q] || (ov == bv[qm][m][q] && oi < bi[qm][m][q])) {
            bv[qm][m][q] = ov;
            bi[qm][m][q] = oi;
          }
        }
  }
  if (l15 == 0) {
#pragma unroll
    for (int qm = 0; qm < 2; ++qm)
#pragma unroll
      for (int m = 0; m < 4; ++m)
#pragma unroll
        for (int q = 0; q < 4; ++q) {
          const int row = wm * 128 + qm * 64 + m * 16 + l4 * 4 + q;
          cvs[wn * 256 + row] = bv[qm][m][q];
          cis[wn * 256 + row] = bi[qm][m][q];
        }
  }
  __syncthreads();
  if (tid < 256) {
    float v = cvs[tid];
    int bidx = cis[tid];
#pragma unroll
    for (int q = 1; q < 4; ++q) {  // ascending wn -> ascending cols
      const float ov = cvs[q * 256 + tid];
      const int oi = cis[q * 256 + tid];
      if (ov < v) {
        v = ov;
        bidx = oi;
      }
    }
    cand_v[(size_t)by * NBT + bt0 + tid] = v;
    cand_i[(size_t)by * NBT + bt0 + tid] = bidx;
  }
}

// -------- combine + exact fp32 top-2 rescore + loss partial (s_best) -------
__global__ __launch_bounds__(256) void combine_rescore_kernel(
    const float* __restrict__ cand_v, const int* __restrict__ cand_i,
    const float* __restrict__ x, const float* __restrict__ emb,
    const float* __restrict__ enorm, int* __restrict__ idx_ws,
    float* __restrict__ idxf, float* __restrict__ lpart) {
  const int r = blockIdx.x * 256 + threadIdx.x;
  float v1 = INFINITY, v2 = INFINITY;
  int i1 = 0, i2 = 0;
#pragma unroll
  for (int nt = 0; nt < CT; ++nt) {  // ascending nt -> ascending index
    const float v = cand_v[(size_t)nt * NBT + r];
    const int i = cand_i[(size_t)nt * NBT + r];
    if (v < v1) {
      v2 = v1;
      i2 = i1;
      v1 = v;
      i1 = i;
    } else if (v < v2) {
      v2 = v;
      i2 = i;
    }
  }
  const int b = r >> 12, t = r & (NT - 1);
  const float* xb = x + (size_t)b * ND * NT + t;
  const float* e1 = emb + (size_t)i1 * ND;
  const float* e2 = emb + (size_t)i2 * ND;
  float d1 = 0.f, d2 = 0.f;
#pragma unroll 8
  for (int d = 0; d < ND; ++d) {
    const float xv = xb[(size_t)d * NT];
    d1 += xv * e1[d];
    d2 += xv * e2[d];
  }
  const float s1 = enorm[i1] - 2.f * d1;
  const float s2 = enorm[i2] - 2.f * d2;
  const bool take2 = (s2 < s1 || (s2 == s1 && i2 < i1));
  const int best = take2 ? i2 : i1;
  idx_ws[r] = best;
  idxf[r] = (float)best;
  // per-row loss term: sum_d (x-v)^2 - sum_d x^2 = enorm[best] - 2*dot_best
  float lsum = take2 ? s2 : s1;
#pragma unroll
  for (int m = 32; m; m >>= 1) lsum += __shfl_xor(lsum, m);
  __shared__ float wsum[4];
  if ((threadIdx.x & 63) == 0) wsum[threadIdx.x >> 6] = lsum;
  __syncthreads();
  if (threadIdx.x == 0)
    lpart[blockIdx.x] = wsum[0] + wsum[1] + wsum[2] + wsum[3];
}

// ----------------------------------------------- gather (emb -> [B,D,T]) ---
__global__ __launch_bounds__(256) void gather_kernel(
    const float* __restrict__ emb, const int* __restrict__ idx_ws,
    float* __restrict__ vals_out) {
  __shared__ float tile[64][65];
  const int tid = threadIdx.x;
  const int bt0 = blockIdx.x * 64;
  const int d0 = blockIdx.y * 64;
  const int b = bt0 / NT;
  const int t0 = bt0 % NT;
  {
    const int dd4 = (tid & 15) * 4;
    const int ttb = tid >> 4;
#pragma unroll
    for (int p = 0; p < 4; ++p) {
      const int tt = ttb + p * 16;
      const int r = idx_ws[bt0 + tt];
      float4 v = *(const float4*)&emb[(size_t)r * ND + d0 + dd4];
      tile[tt][dd4 + 0] = v.x;
      tile[tt][dd4 + 1] = v.y;
      tile[tt][dd4 + 2] = v.z;
      tile[tt][dd4 + 3] = v.w;
    }
  }
  __syncthreads();
  {
    const int tt4 = (tid & 15) * 4;
    const int ddb = tid >> 4;
#pragma unroll
    for (int p = 0; p < 4; ++p) {
      const int dd = ddb + p * 16;
      float4 v;
      v.x = tile[tt4 + 0][dd];
      v.y = tile[tt4 + 1][dd];
      v.z = tile[tt4 + 2][dd];
      v.w = tile[tt4 + 3][dd];
      const size_t o = (size_t)b * ND * NT + (size_t)(d0 + dd) * NT + t0 + tt4;
      *(float4*)&vals_out[o] = v;
    }
  }
}

// ----------------------------------------------------------------- loss ----
__global__ void loss_kernel(const float* __restrict__ partials, int n,
                            float* __restrict__ out) {
  float s = 0.f;
  for (int i = threadIdx.x; i < n; i += 256) s += partials[i];
#pragma unroll
  for (int m = 32; m; m >>= 1) s += __shfl_xor(s, m);
  __shared__ float wsum[4];
  if ((threadIdx.x & 63) == 0) wsum[threadIdx.x >> 6] = s;
  __syncthreads();
  if (threadIdx.x == 0)
    out[0] = 2.0f * (wsum[0] + wsum[1] + wsum[2] + wsum[3]) /
             (float)((size_t)NB * ND * NT);
}

// --------------------------------------------------------------- launch ----
extern "C" void kernel_launch(void* const* d_in, const int* in_sizes, int n_in,
                              void* d_out, int out_size, void* d_ws,
                              size_t ws_size, hipStream_t stream) {
  const float* x = (const float*)d_in[0];
  const float* emb = (const float*)d_in[1];
  float* out = (float*)d_out;
  float* vals_out = out;                         // [B, D, T]
  float* idxf_out = out + (size_t)NB * ND * NT;  // [B, T] as float
  float* loss_out = idxf_out + NBT;              // scalar

  u16* xh = (u16*)d_ws;                            // NBT*ND
  u16* xl = xh + (size_t)NBT * ND;                 // NBT*ND
  u16* eh2 = xl + (size_t)NBT * ND;                // NK*ND
  u16* el2 = eh2 + (size_t)NK * ND;                // NK*ND
  float* enorm = (float*)(el2 + (size_t)NK * ND);  // NK
  float* cand_v = enorm + NK;                      // CT * NBT
  int* cand_i = (int*)(cand_v + (size_t)CT * NBT);
  int* idx_ws = cand_i + (size_t)CT * NBT;  // NBT
  float* partials = (float*)(idx_ws + NBT); // 2048 (x^2) + 64 (rescore)

  conv_e_kernel<<<NK / 4, 256, 0, stream>>>(emb, eh2, el2, enorm);
  conv_x_kernel<<<dim3(NBT / 64, ND / 64), 256, 0, stream>>>(x, xh, xl,
                                                             partials);
  argmin_gemm_kernel<<<1024, 512, 0, stream>>>(xh, xl, eh2, el2, enorm, cand_v,
                                               cand_i);
  combine_rescore_kernel<<<NBT / 256, 256, 0, stream>>>(
      cand_v, cand_i, x, emb, enorm, idx_ws, idxf_out, partials + 2048);
  gather_kernel<<<dim3(NBT / 64, ND / 64), 256, 0, stream>>>(emb, idx_ws,
                                                             vals_out);
  loss_kernel<<<1, 256, 0, stream>>>(partials, 2048 + 64, loss_out);
}

// Round 8
// 275.614 us; speedup vs baseline: 1.3334x; 1.0499x over previous
//
#include <hip/hip_runtime.h>
#include <cstddef>
#include <cstdint>

#define NB 4
#define ND 512
#define NT 4096
#define NK 4096
#define NBT (NB * NT)
#define BKR 32         // real-k chunk
#define NCH (ND / BKR) // 16 chunks
#define CT (NK / 256)  // 16 candidate tiles

typedef __attribute__((ext_vector_type(4))) float f32x4;
typedef __attribute__((ext_vector_type(8))) short short8;
typedef __attribute__((ext_vector_type(8))) unsigned short u16x8;
typedef unsigned short u16;

__device__ inline u16 f2bf_rn(float f) {
  unsigned u = __float_as_uint(f);
  return (u16)((u + 0x7FFFu + ((u >> 16) & 1u)) >> 16);
}
__device__ inline float bf2f(u16 h) {
  return __uint_as_float(((unsigned)h) << 16);
}
__device__ inline void gload16(void* lds_p, const void* g) {
  __builtin_amdgcn_global_load_lds(
      (const __attribute__((address_space(1))) unsigned int*)g,
      (__attribute__((address_space(3))) unsigned int*)lds_p, 16, 0, 0);
}

// ---------------------------------------------------- e conversion + norm --
__global__ void conv_e_kernel(const float* __restrict__ emb,
                              u16* __restrict__ eh2, u16* __restrict__ el2,
                              float* __restrict__ enorm) {
  int row = blockIdx.x * 4 + (threadIdx.x >> 6);
  int l = threadIdx.x & 63;
  const float* e = emb + (size_t)row * ND;
  float s = 0.f;
#pragma unroll
  for (int i = 0; i < ND / 64; ++i) {
    int idx = l + i * 64;
    float v = e[idx];
    s += v * v;
    float v2 = 2.f * v;
    u16 h = f2bf_rn(v2);
    u16 lo = f2bf_rn(v2 - bf2f(h));
    eh2[(size_t)row * ND + idx] = h;
    el2[(size_t)row * ND + idx] = lo;
  }
#pragma unroll
  for (int m = 32; m; m >>= 1) s += __shfl_xor(s, m);
  if (l == 0) enorm[row] = s;
}

// ------------------- x conversion (+ transpose) + sum(x^2) partials --------
__global__ __launch_bounds__(256) void conv_x_kernel(const float* __restrict__ x,
                                                     u16* __restrict__ xh,
                                                     u16* __restrict__ xl,
                                                     float* __restrict__ xsq) {
  __shared__ float tile[64][68];
  const int tid = threadIdx.x;
  const int bt0 = blockIdx.x * 64, d0 = blockIdx.y * 64;
  const int b = bt0 / NT, t0 = bt0 % NT;
  const float* xb = x + (size_t)b * ND * NT;
  float s2 = 0.f;
  {
    const int tt4 = (tid & 15) * 4, ddb = tid >> 4;
#pragma unroll
    for (int p = 0; p < 4; ++p) {
      const int dd = ddb + p * 16;
      float4 v = *(const float4*)&xb[(size_t)(d0 + dd) * NT + t0 + tt4];
      s2 += v.x * v.x + v.y * v.y + v.z * v.z + v.w * v.w;
      *(float4*)&tile[dd][tt4] = v;
    }
  }
  __syncthreads();
  {
    const int t_loc = tid >> 2, dg = tid & 3;
    u16 hs[16], ls[16];
#pragma unroll
    for (int j = 0; j < 16; ++j) {
      float f = tile[dg * 16 + j][t_loc];
      u16 h = f2bf_rn(f);
      hs[j] = h;
      ls[j] = f2bf_rn(f - bf2f(h));
    }
    const size_t base = (size_t)(bt0 + t_loc) * ND + d0 + dg * 16;
    *(u16x8*)&xh[base] = *(const u16x8*)&hs[0];
    *(u16x8*)&xh[base + 8] = *(const u16x8*)&hs[8];
    *(u16x8*)&xl[base] = *(const u16x8*)&ls[0];
    *(u16x8*)&xl[base + 8] = *(const u16x8*)&ls[8];
  }
#pragma unroll
  for (int m = 32; m; m >>= 1) s2 += __shfl_xor(s2, m);
  __shared__ float wsum[4];
  if ((tid & 63) == 0) wsum[tid >> 6] = s2;
  __syncthreads();
  if (tid == 0)
    xsq[blockIdx.y * gridDim.x + blockIdx.x] =
        wsum[0] + wsum[1] + wsum[2] + wsum[3];
}

// ------------------------------------------------- 3-phase GEMM + argmin ---
// 256x256 tile, 8 waves (2M x 4N). Quad-operand LDS residency: per real-k
// chunk of 32, stage aH=xh, aL=xl, bH=eh2, bL=el2 (4 x 16 KB) and compute
// all three products (aH*bH + aH*bL + aL*bH) from ONE staging -> 1.5x less
// LDS read/write + global fetch vs the augmented-K' form. Double-buffered
// (128 KiB). Round-5-proven schedule: ONE barrier/phase, spread staging,
// counted vmcnt 6/6/4 (tail 2/0/0), setprio, XCD-bijective block swizzle.
// LDS rows are 64 B: swizzle slot = l4 ^ ((row>>1)&3) -> 2-way max (free);
// stage source pre-swizzled with the same involution (both-sides rule).
__device__ __forceinline__ void stage_op(
    u16 (&lds)[2][4][256][BKR], int bn, int op, int tn,
    const u16* __restrict__ src, int rowbase, int w, int l) {
  if (tn >= NCH) return;
  const int kA = tn * BKR;
#pragma unroll
  for (int i = 0; i < 2; ++i) {
    const int rowL = i * 128 + w * 16 + (l >> 2);
    const int gslot = (l & 3) ^ ((rowL >> 1) & 3);
    gload16(&lds[bn][op][i * 128 + w * 16][0],
            &src[(size_t)(rowbase + rowL) * ND + kA + gslot * 8]);
  }
}

__global__ __launch_bounds__(512, 2) void argmin_gemm_kernel(
    const u16* __restrict__ xh, const u16* __restrict__ xl,
    const u16* __restrict__ eh2, const u16* __restrict__ el2,
    const float* __restrict__ enorm, float* __restrict__ cand_v,
    int* __restrict__ cand_i) {
  __shared__ u16 lds[2][4][256][BKR];  // [buf][aH,aL,bH,bL][row][k] = 128 KiB
  const int tid = threadIdx.x;
  const int w = tid >> 6, l = tid & 63;
  const int l15 = l & 15, l4 = l >> 4;
  const int wm = w >> 2, wn = w & 3;
  // XCD-aware bijective swizzle: nwg=1024, 128 blocks per XCD chunk.
  const int id = blockIdx.x;
  const int id_sw = (id & 7) * 128 + (id >> 3);
  const int bx = id_sw & 63, by = id_sw >> 6;
  const int bt0 = bx * 256, c0g = by * 256;

  f32x4 acc[2][4][2][2];  // [qm][m][qn][n]
#pragma unroll
  for (int qm = 0; qm < 2; ++qm)
#pragma unroll
    for (int m = 0; m < 4; ++m)
#pragma unroll
      for (int qn = 0; qn < 2; ++qn)
#pragma unroll
        for (int n = 0; n < 2; ++n) acc[qm][m][qn][n] = (f32x4)0.f;

  short8 aH[8], aL[8], bH[4], bL[4];

#define SLOT(row) (((l4) ^ (((row) >> 1) & 3)) * 8)
#define DS_A(AF, OP)                                                     \
  _Pragma("unroll") for (int qm = 0; qm < 2; ++qm) {                     \
    _Pragma("unroll") for (int m = 0; m < 4; ++m) {                      \
      const int row = wm * 128 + qm * 64 + m * 16 + l15;                 \
      AF[qm * 4 + m] = *(const short8*)&lds[cur][OP][row][SLOT(row)];    \
    }                                                                    \
  }
#define DS_B(BF, OP)                                                     \
  _Pragma("unroll") for (int qn = 0; qn < 2; ++qn) {                     \
    _Pragma("unroll") for (int n = 0; n < 2; ++n) {                      \
      const int row = wn * 64 + qn * 32 + n * 16 + l15;                  \
      BF[qn * 2 + n] = *(const short8*)&lds[cur][OP][row][SLOT(row)];    \
    }                                                                    \
  }
#define MMP(AF, BF)                                                      \
  __builtin_amdgcn_s_setprio(1);                                         \
  _Pragma("unroll") for (int qm = 0; qm < 2; ++qm) {                     \
    _Pragma("unroll") for (int m = 0; m < 4; ++m) {                      \
      _Pragma("unroll") for (int qn = 0; qn < 2; ++qn) {                 \
        _Pragma("unroll") for (int n = 0; n < 2; ++n) {                  \
          acc[qm][m][qn][n] = __builtin_amdgcn_mfma_f32_16x16x32_bf16(   \
              AF[qm * 4 + m], BF[qn * 2 + n], acc[qm][m][qn][n], 0, 0,   \
              0);                                                        \
        }                                                                \
      }                                                                  \
    }                                                                    \
  }                                                                      \
  __builtin_amdgcn_s_setprio(0);
#define BAR __builtin_amdgcn_s_barrier()
#define LGK                                              \
  asm volatile("s_waitcnt lgkmcnt(0)" ::: "memory");     \
  __builtin_amdgcn_sched_barrier(0)
#define VMC(N) asm volatile("s_waitcnt vmcnt(" #N ")" ::: "memory")

  // prologue: stage chunk 0 (order aH,bH,bL,aL; 8 loads/thread);
  // VMC(4) drains aH,bH -> loop invariant Q=[bL(c)2, aL(c)2].
  stage_op(lds, 0, 0, 0, xh, bt0, w, l);   // aH
  stage_op(lds, 0, 2, 0, eh2, c0g, w, l);  // bH
  stage_op(lds, 0, 3, 0, el2, c0g, w, l);  // bL
  stage_op(lds, 0, 1, 0, xl, bt0, w, l);   // aL
  VMC(4);
  BAR;

  for (int t = 0; t < NCH; ++t) {
    const int cur = t & 1;
    const int nb = cur ^ 1;
    const int tn = t + 1;
    const bool last = (t == NCH - 1);
    // ---- P0: stage aH,bH(c+1); read aH,bH(c); MFMA aH*bH ----
    stage_op(lds, nb, 0, tn, xh, bt0, w, l);
    stage_op(lds, nb, 2, tn, eh2, c0g, w, l);
    DS_A(aH, 0);
    DS_B(bH, 2);
    LGK;
    MMP(aH, bH);
    if (last) {       // Q=[bL,aL]: drain bL
      VMC(2);
    } else {          // Q=[bL(c)2,aL(c)2,aHbH(c+1)4]=8: drain bL(c)
      VMC(6);
    }
    BAR;
    // ---- P1: stage bL(c+1); read bL(c); MFMA aH*bL ----
    stage_op(lds, nb, 3, tn, el2, c0g, w, l);
    DS_B(bL, 3);
    LGK;
    MMP(aH, bL);
    if (last) {
      VMC(0);
    } else {          // Q=[aL(c)2,aHbH(c+1)4,bL(c+1)2]=8: drain aL(c)
      VMC(6);
    }
    BAR;
    // ---- P2: stage aL(c+1); read aL(c); MFMA aL*bH ----
    stage_op(lds, nb, 1, tn, xl, bt0, w, l);
    DS_A(aL, 1);
    LGK;
    MMP(aL, bH);
    if (last) {
      VMC(0);
    } else {          // Q=[aHbH(c+1)4,bL(c+1)2,aL(c+1)2]=8: drain aH,bH
      VMC(4);
    }
    BAR;
  }
#undef SLOT
#undef DS_A
#undef DS_B
#undef MMP
#undef BAR
#undef LGK
#undef VMC

  // ---- epilogue: per-row argmin over this block's 256 cols ----
  __syncthreads();  // all loads drained (vmcnt 0 at exit); LDS reused below
  float* cvs = (float*)&lds[0][0][0][0];  // [4][256]
  int* cis = (int*)(cvs + 4 * 256);       // [4][256]

  float bv[2][4][4];
  int bi[2][4][4];
#pragma unroll
  for (int qm = 0; qm < 2; ++qm)
#pragma unroll
    for (int m = 0; m < 4; ++m)
#pragma unroll
      for (int q = 0; q < 4; ++q) {
        bv[qm][m][q] = INFINITY;
        bi[qm][m][q] = 0;
      }
#pragma unroll
  for (int qn = 0; qn < 2; ++qn)  // ascending col order -> first-min ties
#pragma unroll
    for (int n = 0; n < 2; ++n) {
      const int col = c0g + wn * 64 + qn * 32 + n * 16 + l15;
      const float en = enorm[col];
#pragma unroll
      for (int qm = 0; qm < 2; ++qm)
#pragma unroll
        for (int m = 0; m < 4; ++m)
#pragma unroll
          for (int q = 0; q < 4; ++q) {
            const float s = en - acc[qm][m][qn][n][q];
            if (s < bv[qm][m][q]) {
              bv[qm][m][q] = s;
              bi[qm][m][q] = col;
            }
          }
    }
#pragma unroll
  for (int msk = 1; msk < 16; msk <<= 1) {
#pragma unroll
    for (int qm = 0; qm < 2; ++qm)
#pragma unroll
      for (int m = 0; m < 4; ++m)
#pragma unroll
        for (int q = 0; q < 4; ++q) {
          const float ov = __shfl_xor(bv[qm][m][q], msk);
          const int oi = __shfl_xor(bi[qm][m][q], msk);
          if (ov < bv[qm][m][q] || (ov == bv[qm][m][q] && oi < bi[qm][m][q])) {
            bv[qm][m][q] = ov;
            bi[qm][m][q] = oi;
          }
        }
  }
  if (l15 == 0) {
#pragma unroll
    for (int qm = 0; qm < 2; ++qm)
#pragma unroll
      for (int m = 0; m < 4; ++m)
#pragma unroll
        for (int q = 0; q < 4; ++q) {
          const int row = wm * 128 + qm * 64 + m * 16 + l4 * 4 + q;
          cvs[wn * 256 + row] = bv[qm][m][q];
          cis[wn * 256 + row] = bi[qm][m][q];
        }
  }
  __syncthreads();
  if (tid < 256) {
    float v = cvs[tid];
    int bidx = cis[tid];
#pragma unroll
    for (int q = 1; q < 4; ++q) {  // ascending wn -> ascending cols
      const float ov = cvs[q * 256 + tid];
      const int oi = cis[q * 256 + tid];
      if (ov < v) {
        v = ov;
        bidx = oi;
      }
    }
    cand_v[(size_t)by * NBT + bt0 + tid] = v;
    cand_i[(size_t)by * NBT + bt0 + tid] = bidx;
  }
}

// -------- combine + exact fp32 top-2 rescore + loss partial (s_best) -------
__global__ __launch_bounds__(256) void combine_rescore_kernel(
    const float* __restrict__ cand_v, const int* __restrict__ cand_i,
    const float* __restrict__ x, const float* __restrict__ emb,
    const float* __restrict__ enorm, int* __restrict__ idx_ws,
    float* __restrict__ idxf, float* __restrict__ lpart) {
  const int r = blockIdx.x * 256 + threadIdx.x;
  float v1 = INFINITY, v2 = INFINITY;
  int i1 = 0, i2 = 0;
#pragma unroll
  for (int nt = 0; nt < CT; ++nt) {  // ascending nt -> ascending index
    const float v = cand_v[(size_t)nt * NBT + r];
    const int i = cand_i[(size_t)nt * NBT + r];
    if (v < v1) {
      v2 = v1;
      i2 = i1;
      v1 = v;
      i1 = i;
    } else if (v < v2) {
      v2 = v;
      i2 = i;
    }
  }
  const int b = r >> 12, t = r & (NT - 1);
  const float* xb = x + (size_t)b * ND * NT + t;
  const float* e1 = emb + (size_t)i1 * ND;
  const float* e2 = emb + (size_t)i2 * ND;
  float d1 = 0.f, d2 = 0.f;
#pragma unroll 8
  for (int d = 0; d < ND; ++d) {
    const float xv = xb[(size_t)d * NT];
    d1 += xv * e1[d];
    d2 += xv * e2[d];
  }
  const float s1 = enorm[i1] - 2.f * d1;
  const float s2 = enorm[i2] - 2.f * d2;
  const bool take2 = (s2 < s1 || (s2 == s1 && i2 < i1));
  const int best = take2 ? i2 : i1;
  idx_ws[r] = best;
  idxf[r] = (float)best;
  // per-row loss term: sum_d (x-v)^2 - sum_d x^2 = enorm[best] - 2*dot_best
  float lsum = take2 ? s2 : s1;
#pragma unroll
  for (int m = 32; m; m >>= 1) lsum += __shfl_xor(lsum, m);
  __shared__ float wsum[4];
  if ((threadIdx.x & 63) == 0) wsum[threadIdx.x >> 6] = lsum;
  __syncthreads();
  if (threadIdx.x == 0)
    lpart[blockIdx.x] = wsum[0] + wsum[1] + wsum[2] + wsum[3];
}

// ----------------------------------------------- gather (emb -> [B,D,T]) ---
__global__ __launch_bounds__(256) void gather_kernel(
    const float* __restrict__ emb, const int* __restrict__ idx_ws,
    float* __restrict__ vals_out) {
  __shared__ float tile[64][65];
  const int tid = threadIdx.x;
  const int bt0 = blockIdx.x * 64;
  const int d0 = blockIdx.y * 64;
  const int b = bt0 / NT;
  const int t0 = bt0 % NT;
  {
    const int dd4 = (tid & 15) * 4;
    const int ttb = tid >> 4;
#pragma unroll
    for (int p = 0; p < 4; ++p) {
      const int tt = ttb + p * 16;
      const int r = idx_ws[bt0 + tt];
      float4 v = *(const float4*)&emb[(size_t)r * ND + d0 + dd4];
      tile[tt][dd4 + 0] = v.x;
      tile[tt][dd4 + 1] = v.y;
      tile[tt][dd4 + 2] = v.z;
      tile[tt][dd4 + 3] = v.w;
    }
  }
  __syncthreads();
  {
    const int tt4 = (tid & 15) * 4;
    const int ddb = tid >> 4;
#pragma unroll
    for (int p = 0; p < 4; ++p) {
      const int dd = ddb + p * 16;
      float4 v;
      v.x = tile[tt4 + 0][dd];
      v.y = tile[tt4 + 1][dd];
      v.z = tile[tt4 + 2][dd];
      v.w = tile[tt4 + 3][dd];
      const size_t o = (size_t)b * ND * NT + (size_t)(d0 + dd) * NT + t0 + tt4;
      *(float4*)&vals_out[o] = v;
    }
  }
}

// ----------------------------------------------------------------- loss ----
__global__ void loss_kernel(const float* __restrict__ partials, int n,
                            float* __restrict__ out) {
  float s = 0.f;
  for (int i = threadIdx.x; i < n; i += 256) s += partials[i];
#pragma unroll
  for (int m = 32; m; m >>= 1) s += __shfl_xor(s, m);
  __shared__ float wsum[4];
  if ((threadIdx.x & 63) == 0) wsum[threadIdx.x >> 6] = s;
  __syncthreads();
  if (threadIdx.x == 0)
    out[0] = 2.0f * (wsum[0] + wsum[1] + wsum[2] + wsum[3]) /
             (float)((size_t)NB * ND * NT);
}

// --------------------------------------------------------------- launch ----
extern "C" void kernel_launch(void* const* d_in, const int* in_sizes, int n_in,
                              void* d_out, int out_size, void* d_ws,
                              size_t ws_size, hipStream_t stream) {
  const float* x = (const float*)d_in[0];
  const float* emb = (const float*)d_in[1];
  float* out = (float*)d_out;
  float* vals_out = out;                         // [B, D, T]
  float* idxf_out = out + (size_t)NB * ND * NT;  // [B, T] as float
  float* loss_out = idxf_out + NBT;              // scalar

  u16* xh = (u16*)d_ws;                            // NBT*ND
  u16* xl = xh + (size_t)NBT * ND;                 // NBT*ND
  u16* eh2 = xl + (size_t)NBT * ND;                // NK*ND
  u16* el2 = eh2 + (size_t)NK * ND;                // NK*ND
  float* enorm = (float*)(el2 + (size_t)NK * ND);  // NK
  float* cand_v = enorm + NK;                      // CT * NBT
  int* cand_i = (int*)(cand_v + (size_t)CT * NBT);
  int* idx_ws = cand_i + (size_t)CT * NBT;  // NBT
  float* partials = (float*)(idx_ws + NBT); // 2048 (x^2) + 64 (rescore)

  conv_e_kernel<<<NK / 4, 256, 0, stream>>>(emb, eh2, el2, enorm);
  conv_x_kernel<<<dim3(NBT / 64, ND / 64), 256, 0, stream>>>(x, xh, xl,
                                                             partials);
  argmin_gemm_kernel<<<1024, 512, 0, stream>>>(xh, xl, eh2, el2, enorm, cand_v,
                                               cand_i);
  combine_rescore_kernel<<<NBT / 256, 256, 0, stream>>>(
      cand_v, cand_i, x, emb, enorm, idx_ws, idxf_out, partials + 2048);
  gather_kernel<<<dim3(NBT / 64, ND / 64), 256, 0, stream>>>(emb, idx_ws,
                                                             vals_out);
  loss_kernel<<<1, 256, 0, stream>>>(partials, 2048 + 64, loss_out);
}